// Round 2
// baseline (1035.887 us; speedup 1.0000x reference)
//
#include <hip/hip_runtime.h>

#define IN_DIM  8192
#define OUT_DIM 8192
#define TPB 256
#define COLS_PER_BLOCK (TPB * 4)              // 1024 columns per block (float4/thread)
#define ROWS_PER_BLOCK 64
#define NCHUNK (IN_DIM / ROWS_PER_BLOCK)      // 128 row-chunks
#define PROBE_PASSES 16                       // 16 x 268 MB = 4.29 GB: > 161 us even at 20 TB/s,
                                              // so the probe ALWAYS lands in the rocprof top-5.

typedef float f4 __attribute__((ext_vector_type(4)));

// Phase 1: each block reduces a 64-row x 1024-col slab of W into per-chunk
// partials (no atomics).  pl = sum c*W - r*|W|, pu = sum c*W + r*|W|,
// c=(l+u)/2, r=(u-l)/2.
// ws layout: [bound(2)][chunk(128)][col(8192)] floats = 8 MB.
// UNCHANGED from the 353.4 us baseline -- this is a measurement round.
__global__ void __launch_bounds__(TPB) ibp_partial_kernel(const float* __restrict__ l,
                                                          const float* __restrict__ u,
                                                          const float* __restrict__ W,
                                                          float* __restrict__ ws) {
    __shared__ float sc[ROWS_PER_BLOCK];
    __shared__ float sr[ROWS_PER_BLOCK];

    const int t    = threadIdx.x;
    const int col0 = blockIdx.x * COLS_PER_BLOCK + t * 4;
    const int row0 = blockIdx.y * ROWS_PER_BLOCK;

    if (t < ROWS_PER_BLOCK) {
        float lv = l[row0 + t];
        float uv = u[row0 + t];
        sc[t] = 0.5f * (lv + uv);
        sr[t] = 0.5f * (uv - lv);
    }
    __syncthreads();

    float cwx = 0.f, cwy = 0.f, cwz = 0.f, cww = 0.f;   // sum c*W
    float rax = 0.f, ray = 0.f, raz = 0.f, raw = 0.f;   // sum r*|W|

    const f4* Wp = reinterpret_cast<const f4*>(
        W + (size_t)row0 * OUT_DIM + col0);

    #pragma unroll 8
    for (int i = 0; i < ROWS_PER_BLOCK; ++i) {
        f4 w = __builtin_nontemporal_load(&Wp[(size_t)i * (OUT_DIM / 4)]);
        float c = sc[i];
        float r = sr[i];
        cwx = fmaf(c, w.x, cwx);  rax = fmaf(r, fabsf(w.x), rax);
        cwy = fmaf(c, w.y, cwy);  ray = fmaf(r, fabsf(w.y), ray);
        cwz = fmaf(c, w.z, cwz);  raz = fmaf(r, fabsf(w.z), raz);
        cww = fmaf(c, w.w, cww);  raw = fmaf(r, fabsf(w.w), raw);
    }

    f4 pl = {cwx - rax, cwy - ray, cwz - raz, cww - raw};
    f4 pu = {cwx + rax, cwy + ray, cwz + raz, cww + raw};

    f4* wsl = reinterpret_cast<f4*>(
        ws + (size_t)blockIdx.y * OUT_DIM + col0);
    f4* wsu = reinterpret_cast<f4*>(
        ws + (size_t)NCHUNK * OUT_DIM + (size_t)blockIdx.y * OUT_DIM + col0);
    *wsl = pl;
    *wsu = pu;
}

// Phase 2: one thread per (bound, col): sum NCHUNK partials + bias.
// UNCHANGED from baseline.
__global__ void __launch_bounds__(TPB) ibp_reduce_kernel(const float* __restrict__ ws,
                                                         const float* __restrict__ bias,
                                                         float* __restrict__ out) {
    const int t = blockIdx.x * TPB + threadIdx.x;   // 0 .. 16383
    const int b = t >> 13;                          // bound index (0=l, 1=u)
    const int j = t & (OUT_DIM - 1);                // column

    const float* p = ws + (size_t)b * NCHUNK * OUT_DIM + j;
    float s = 0.f;
    #pragma unroll 8
    for (int c = 0; c < NCHUNK; ++c)
        s += p[(size_t)c * OUT_DIM];

    out[t] = s + bias[j];
}

// PROBE (measurement round only): stream W 16x with phase 1's exact access
// pattern (same grid, same nt dwordx4 loads, 32 KB row stride).  4.29 GB of
// loads guarantees dur > 161 us at any feasible BW, so it lands in the
// rocprof top-5 with its own dur / FETCH_SIZE / hbm_gbps row:
//   FETCH ~ 4.3 GB @ ~6.4 TB/s  -> W streams from HBM (floor ~42 us/pass)
//   FETCH << 4.3 GB             -> W is L3-resident; L3 rate = 4.29GB / dur
// Per-pass asm barriers ("+v" + memory clobber) defeat cross-pass load CSE;
// the final asm keeps accumulators live (no DCE, rule #17).  Writes nothing.
__global__ void __launch_bounds__(TPB) ibp_probe_kernel(const float* __restrict__ W) {
    const int t    = threadIdx.x;
    const int col0 = blockIdx.x * COLS_PER_BLOCK + t * 4;
    const int row0 = blockIdx.y * ROWS_PER_BLOCK;

    const f4* Wp = reinterpret_cast<const f4*>(
        W + (size_t)row0 * OUT_DIM + col0);

    float ax = 0.f, ay = 0.f, az = 0.f, aw = 0.f;

    #pragma unroll 1
    for (int p = 0; p < PROBE_PASSES; ++p) {
        #pragma unroll 8
        for (int i = 0; i < ROWS_PER_BLOCK; ++i) {
            f4 w = __builtin_nontemporal_load(&Wp[(size_t)i * (OUT_DIM / 4)]);
            ax += w.x; ay += w.y; az += w.z; aw += w.w;
        }
        asm volatile("" : "+v"(ax), "+v"(ay), "+v"(az), "+v"(aw) :: "memory");
    }
    asm volatile("" :: "v"(ax), "v"(ay), "v"(az), "v"(aw));
}

extern "C" void kernel_launch(void* const* d_in, const int* in_sizes, int n_in,
                              void* d_out, int out_size, void* d_ws, size_t ws_size,
                              hipStream_t stream) {
    const float* l    = (const float*)d_in[0];
    const float* u    = (const float*)d_in[1];
    const float* W    = (const float*)d_in[2];
    const float* bias = (const float*)d_in[3];
    float* out = (float*)d_out;
    float* ws  = (float*)d_ws;   // 2 * 128 * 8192 floats = 8 MB (ws_size >= 1 GiB)

    dim3 grid1(OUT_DIM / COLS_PER_BLOCK, NCHUNK);   // (8, 128) = 1024 blocks
    ibp_partial_kernel<<<grid1, TPB, 0, stream>>>(l, u, W, ws);

    ibp_reduce_kernel<<<(2 * OUT_DIM) / TPB, TPB, 0, stream>>>(ws, bias, out);

    // Measurement probe -- removed next round once the fill-count question is
    // resolved.
    ibp_probe_kernel<<<grid1, TPB, 0, stream>>>(W);
}